// Round 11
// baseline (329.943 us; speedup 1.0000x reference)
//
#include <hip/hip_runtime.h>

typedef __bf16 bf16_t;
typedef __attribute__((ext_vector_type(8))) __bf16 bf16x8;
typedef __attribute__((ext_vector_type(4))) __bf16 bf16x4;
typedef __attribute__((ext_vector_type(4))) float f32x4;
typedef __attribute__((ext_vector_type(16))) float f32x16;
typedef __attribute__((ext_vector_type(4))) unsigned u32x4;

// async global->LDS, 16B per lane. LDS dest must be wave-uniform base + lane*16.
#define GLL16(gsrc, ldst)                                                                   \
  __builtin_amdgcn_global_load_lds(                                                         \
      (const __attribute__((address_space(1))) unsigned int*)(gsrc),                        \
      (__attribute__((address_space(3))) unsigned int*)(ldst), 16, 0, 0)

// v_permlane32_swap_b32: a'[0:31]=a[0:31], a'[32:63]=b[0:31]; b'[0:31]=a[32:63], b'[32:63]=b[32:63]
#define SWAP32(x, y) asm("v_permlane32_swap_b32 %0, %1" : "+v"(x), "+v"(y))

// ---------------- problem dims ----------------
#define BATCH 16
#define TT    2048
#define DD    512
#define FF    256
#define MTOT  (BATCH * TT)   // 32768

static __device__ __forceinline__ unsigned pk2(float a, float b) {
  unsigned short ua = __builtin_bit_cast(unsigned short, (bf16_t)a);
  unsigned short ub = __builtin_bit_cast(unsigned short, (bf16_t)b);
  return (unsigned)ua | ((unsigned)ub << 16);
}

// ---------------- merged cast kernel ----------------
__global__ __launch_bounds__(256) void cast_all_kernel(const float* __restrict__ x,
                                                       bf16_t* __restrict__ xb,
                                                       const float* __restrict__ Wqkv,
                                                       const float* __restrict__ Wout,
                                                       bf16_t* __restrict__ WqkvT,
                                                       bf16_t* __restrict__ WoutT) {
  const int t0 = blockIdx.x * blockDim.x + threadIdx.x;
  const int stride = gridDim.x * blockDim.x;
  const int n4 = (MTOT * DD) / 4;
  for (int i = t0; i < n4; i += stride) {
    float4 v = ((const float4*)x)[i];
    bf16x4 o;
    o[0] = (bf16_t)v.x; o[1] = (bf16_t)v.y; o[2] = (bf16_t)v.z; o[3] = (bf16_t)v.w;
    ((bf16x4*)xb)[i] = o;
  }
  for (int i = t0; i < 768 * 512 + 512 * 256; i += stride) {
    if (i < 768 * 512) {
      int n = i >> 9, k = i & 511;
      WqkvT[i] = (bf16_t)Wqkv[k * 768 + n];
    } else {
      int i2 = i - 768 * 512;
      int n = i2 >> 8, k = i2 & 255;
      WoutT[i2] = (bf16_t)Wout[k * 512 + n];
    }
  }
}

// ---------------- GEMM 1: X[32768,512] x WqkvT[768,512] -> Q,K row-major, V transposed ----
// 128x128 tile, BK=64 (8 K-steps, half the barriers of BK=32), 64KB LDS -> 2 blocks/CU.
__global__ __launch_bounds__(256) void gemm_qkv_kernel(const bf16_t* __restrict__ A,
                                                       const bf16_t* __restrict__ Bt,
                                                       const float* __restrict__ bias,
                                                       bf16_t* __restrict__ Qo,
                                                       bf16_t* __restrict__ Ko,
                                                       bf16_t* __restrict__ Vt) {
  __shared__ __align__(16) bf16_t Al[2][128 * 64];
  __shared__ __align__(16) bf16_t Bl[2][128 * 64];
  const int tid = threadIdx.x;
  const int l = tid & 63, w = tid >> 6;
  const int g = l >> 4, r = l & 15;
  const int wm = w >> 1, wn = w & 1;
  const int lin = blockIdx.x;                       // 1536 blocks
  const int wid = (lin & 7) * 192 + (lin >> 3);     // bijective chunked XCD swizzle
  const int m0 = (wid / 6) * 128;
  const int n0 = (wid % 6) * 128;
  const int lda = 512, ldb = 512;
  const bf16_t* Abase = A + (size_t)m0 * lda;
  const bf16_t* Bbase = Bt + (size_t)n0 * ldb;

  f32x4 acc[4][4] = {};

  auto stage = [&](int kt, int bufi) {
    const int k0 = kt * 64;
#pragma unroll
    for (int rnd = 0; rnd < 4; ++rnd) {             // 128 rows x 8 chunks of 16B
      int idx = rnd * 256 + tid;
      int row = idx >> 3, d = idx & 7;
      int sc = d ^ (row & 7);
      GLL16(Abase + row * lda + k0 + sc * 8, &Al[bufi][idx * 8]);
    }
#pragma unroll
    for (int rnd = 0; rnd < 4; ++rnd) {
      int idx = rnd * 256 + tid;
      int row = idx >> 3, d = idx & 7;
      int sc = d ^ (row & 7);
      GLL16(Bbase + row * ldb + k0 + sc * 8, &Bl[bufi][idx * 8]);
    }
  };

  stage(0, 0);
  __syncthreads();
  int buf = 0;
  const int NK = 512 / 64;
  for (int kt = 0; kt < NK; ++kt) {
    if (kt + 1 < NK) stage(kt + 1, buf ^ 1);
#pragma unroll
    for (int kk = 0; kk < 2; ++kk) {
      bf16x8 af[4], bfr[4];
#pragma unroll
      for (int mi = 0; mi < 4; ++mi) {
        int row = wm * 64 + mi * 16 + r;
        int cc = (kk * 4 + g) ^ (row & 7);
        af[mi] = *(const bf16x8*)&Al[buf][row * 64 + cc * 8];
      }
#pragma unroll
      for (int ni = 0; ni < 4; ++ni) {
        int row = wn * 64 + ni * 16 + r;
        int cc = (kk * 4 + g) ^ (row & 7);
        bfr[ni] = *(const bf16x8*)&Bl[buf][row * 64 + cc * 8];
      }
#pragma unroll
      for (int mi = 0; mi < 4; ++mi)
#pragma unroll
        for (int ni = 0; ni < 4; ++ni)
          acc[mi][ni] = __builtin_amdgcn_mfma_f32_16x16x32_bf16(af[mi], bfr[ni], acc[mi][ni], 0, 0, 0);
    }
    __syncthreads();
    buf ^= 1;
  }

  const int qsel = n0 >> 8;
#pragma unroll
  for (int mi = 0; mi < 4; ++mi) {
    int row0 = m0 + wm * 64 + mi * 16 + g * 4;
#pragma unroll
    for (int ni = 0; ni < 4; ++ni) {
      int col = n0 + wn * 64 + ni * 16 + r;
      float bv = bias[col];
      int cl = col & 255;
      if (qsel == 2) {
        bf16x4 pk;
#pragma unroll
        for (int i = 0; i < 4; ++i) pk[i] = (bf16_t)(acc[mi][ni][i] + bv);
        int b = row0 >> 11, t0 = row0 & 2047;
        *(bf16x4*)&Vt[((size_t)(b * 256 + cl)) * 2048 + t0] = pk;
      } else {
        bf16_t* dst = (qsel == 0) ? Qo : Ko;
#pragma unroll
        for (int i = 0; i < 4; ++i)
          dst[(size_t)(row0 + i) * 256 + cl] = (bf16_t)(acc[mi][ni][i] + bv);
      }
    }
  }
}

// ---------------- flash attention (kv-split x2, 32x32x16 MFMA, q_w=32) ----------------
// 512 blocks = 16 batches x 16 qblk(128) x 2 kv-splits, XCD-chunk-swizzled.
// 256 threads = 4 waves, each wave owns 32 q rows (q = lane&31, lane-local).
// KVBLK=32, LDS 64KB dbuf -> 2 blocks/CU, 2 waves/SIMD. P in-register via
// cvt-pack + permlane32_swap. QK accumulator split in two halves (dep-chain /2).
__global__ __launch_bounds__(256, 2) void attn_kernel(const bf16_t* __restrict__ Q,
                                                      const bf16_t* __restrict__ K,
                                                      const bf16_t* __restrict__ Vt,
                                                      bf16_t* __restrict__ ctxp,
                                                      float2* __restrict__ ml) {
  __shared__ __align__(16) bf16_t Kl[2][32 * 256];   // [kv][f], 512B rows, 16B-chunk ^= row&7
  __shared__ __align__(16) bf16_t Vl[2][256 * 32];   // [f][kv], 64B rows, 16B-chunk ^= row&3
  const int tid = threadIdx.x;
  const int l = tid & 63, w = tid >> 6;              // 4 waves
  const int hi = l >> 5, q31 = l & 31;
  const int lin = blockIdx.x;                        // 512 blocks
  const int wid = (lin & 7) * 64 + (lin >> 3);       // chunked XCD swizzle (2 batches/XCD)
  const int b = wid >> 5;
  const int qblk = wid & 15;
  const int s = (wid >> 4) & 1;                      // kv split
  const int q0 = qblk * 128 + w * 32;
  const int kvbase = s * 1024;
  const bf16_t* Kb = K + ((size_t)b * TT) * 256;
  const bf16_t* Vb = Vt + (size_t)b * 256 * TT;

  // Q B-fragments: B[k][q], k = kf*16 + hi*8 + j, q = q31
  bf16x8 qf[16];
  const bf16_t* Qrow = Q + ((size_t)(b * TT) + q0 + q31) * 256;
#pragma unroll
  for (int kf = 0; kf < 16; ++kf) qf[kf] = *(const bf16x8*)(Qrow + kf * 16 + hi * 8);

  f32x16 cacc[8] = {};
  float m_run = -3.0e38f, l_run = 0.0f;

  auto stage = [&](int kv0, int bi) {
#pragma unroll
    for (int rnd = 0; rnd < 4; ++rnd) {  // K tile: 32 rows x 32 chunks of 16B
      int idx = rnd * 256 + tid;
      int row = idx >> 5, d = idx & 31;
      int sc = d ^ (row & 7);
      GLL16(Kb + (size_t)(kv0 + row) * 256 + sc * 8, &Kl[bi][idx * 8]);
    }
#pragma unroll
    for (int rnd = 0; rnd < 4; ++rnd) {  // V tile: 256 rows x 4 chunks of 16B
      int idx = rnd * 256 + tid;
      int R = idx >> 2, d = idx & 3;
      int c = d ^ (R & 3);
      GLL16(Vb + (size_t)R * TT + kv0 + c * 8, &Vl[bi][idx * 8]);
    }
  };

  stage(kvbase, 0);
  __syncthreads();
  int buf = 0;

  for (int t = 0; t < 32; ++t) {
    const int kv0 = kvbase + t * 32;
    if (t + 1 < 32) stage(kv0 + 32, buf ^ 1);      // prefetch next tile under compute

    // S^T[kv32][q32] = K-tile x Q, two independent accumulator chains
    f32x16 sa = {}, sb = {};
    __builtin_amdgcn_s_setprio(1);
#pragma unroll
    for (int kf = 0; kf < 16; kf += 2) {
      int ca = (2 * kf + hi) ^ (q31 & 7);
      int cb = (2 * (kf + 1) + hi) ^ (q31 & 7);
      bf16x8 ka = *(const bf16x8*)&Kl[buf][q31 * 256 + ca * 8];
      bf16x8 kb = *(const bf16x8*)&Kl[buf][q31 * 256 + cb * 8];
      sa = __builtin_amdgcn_mfma_f32_32x32x16_bf16(ka, qf[kf], sa, 0, 0, 0);
      sb = __builtin_amdgcn_mfma_f32_32x32x16_bf16(kb, qf[kf + 1], sb, 0, 0, 0);
    }
    __builtin_amdgcn_s_setprio(0);
    f32x16 st = sa + sb;

    // online softmax; lane state for q=q31, 16 kv values/lane (partner lane+32 has other 16)
    float tmax = -3.0e38f;
#pragma unroll
    for (int i = 0; i < 16; ++i) tmax = fmaxf(tmax, st[i] * 0.0625f);
    tmax = fmaxf(tmax, __shfl_xor(tmax, 32));
    if (!__all(tmax - m_run <= 8.0f)) {            // defer-max
      float mnew = fmaxf(m_run, tmax);
      float alpha = __expf(m_run - mnew);
      l_run *= alpha;
#pragma unroll
      for (int fc = 0; fc < 8; ++fc)
#pragma unroll
        for (int i = 0; i < 16; ++i) cacc[fc][i] *= alpha;
      m_run = mnew;
    }
    float psum = 0.0f;
    float p[16];
#pragma unroll
    for (int i = 0; i < 16; ++i) {
      p[i] = __expf(st[i] * 0.0625f - m_run);      // bounded by e^8; kv=(i&3)+8*(i>>2)+4*hi
      psum += p[i];
    }
    psum += __shfl_xor(psum, 32);
    l_run += psum;

    // P -> bf16 B-frags in-register: pack kv-pairs, swap halves across lane32 boundary.
    unsigned u00 = pk2(p[0], p[1]),  u01 = pk2(p[2], p[3]);
    unsigned u10 = pk2(p[4], p[5]),  u11 = pk2(p[6], p[7]);
    unsigned u20 = pk2(p[8], p[9]),  u21 = pk2(p[10], p[11]);
    unsigned u30 = pk2(p[12], p[13]), u31 = pk2(p[14], p[15]);
    SWAP32(u00, u10);
    SWAP32(u01, u11);
    SWAP32(u20, u30);
    SWAP32(u21, u31);
    u32x4 w0 = {u00, u01, u10, u11};
    u32x4 w1 = {u20, u21, u30, u31};
    bf16x8 pf0 = __builtin_bit_cast(bf16x8, w0);   // P^T[kv 0..15][q], k=hi*8+j
    bf16x8 pf1 = __builtin_bit_cast(bf16x8, w1);   // P^T[kv 16..31][q]

    // PV: ctx^T[f][q] += V^T x P^T ; A-frag row f_loc=q31, k = kv_half local
    __builtin_amdgcn_s_setprio(1);
#pragma unroll
    for (int fc = 0; fc < 8; ++fc) {
      int R = fc * 32 + q31;
      bf16x8 vf0 = *(const bf16x8*)&Vl[buf][R * 32 + ((hi ^ (R & 3)) * 8)];
      bf16x8 vf1 = *(const bf16x8*)&Vl[buf][R * 32 + (((2 + hi) ^ (R & 3)) * 8)];
      cacc[fc] = __builtin_amdgcn_mfma_f32_32x32x16_bf16(vf0, pf0, cacc[fc], 0, 0, 0);
      cacc[fc] = __builtin_amdgcn_mfma_f32_32x32x16_bf16(vf1, pf1, cacc[fc], 0, 0, 0);
    }
    __builtin_amdgcn_s_setprio(0);

    __syncthreads();         // drains vmcnt(0): next tile staged; all waves done with buf
    buf ^= 1;
  }

  // epilogue: normalized partial ctx[q][f], f = fc*32 + 8*qd + 4*hi + i
  float inv = 1.0f / l_run;
  bf16_t* crow = ctxp + (size_t)s * (MTOT * 256) + ((size_t)(b * TT) + q0 + q31) * 256;
#pragma unroll
  for (int fc = 0; fc < 8; ++fc) {
#pragma unroll
    for (int qd = 0; qd < 4; ++qd) {
      bf16x4 o;
#pragma unroll
      for (int i = 0; i < 4; ++i) o[i] = (bf16_t)(cacc[fc][4 * qd + i] * inv);
      *(bf16x4*)(crow + fc * 32 + 8 * qd + 4 * hi) = o;
    }
  }
  if (l < 32) {
    float2 v; v.x = m_run; v.y = l_run;
    ml[s * MTOT + b * TT + q0 + l] = v;
  }
}

// ---------------- merge the two kv-split partials ----------------
__global__ __launch_bounds__(256) void merge_kernel(const bf16_t* __restrict__ c0,
                                                    const bf16_t* __restrict__ c1,
                                                    const float2* __restrict__ ml,
                                                    bf16_t* __restrict__ out) {
  int t = blockIdx.x * 256 + threadIdx.x;          // 32768*64 threads
  int row = t >> 6;
  int fo = (t & 63) * 4;
  float2 a = ml[row];
  float2 bm = ml[MTOT + row];
  float M = fmaxf(a.x, bm.x);
  float w0 = a.y * __expf(a.x - M);
  float w1 = bm.y * __expf(bm.x - M);
  float inv = 1.0f / (w0 + w1);
  w0 *= inv; w1 *= inv;
  size_t off = (size_t)row * 256 + fo;
  bf16x4 v0 = *(const bf16x4*)(c0 + off);
  bf16x4 v1 = *(const bf16x4*)(c1 + off);
  bf16x4 o;
#pragma unroll
  for (int i = 0; i < 4; ++i) o[i] = (bf16_t)((float)v0[i] * w0 + (float)v1[i] * w1);
  *(bf16x4*)(out + off) = o;
}

// ---------------- GEMM 2: ctx[32768,256] x WoutT[512,256] + bias + X -> out fp32 --------
// BK=64 (4 K-steps), 64KB LDS.
__global__ __launch_bounds__(256) void gemm_out_kernel(const bf16_t* __restrict__ A,
                                                       const bf16_t* __restrict__ Bt,
                                                       const float* __restrict__ bias,
                                                       const float* __restrict__ X,
                                                       float* __restrict__ Out) {
  __shared__ __align__(16) bf16_t Al[2][128 * 64];
  __shared__ __align__(16) bf16_t Bl[2][128 * 64];
  const int tid = threadIdx.x;
  const int l = tid & 63, w = tid >> 6;
  const int g = l >> 4, r = l & 15;
  const int wm = w >> 1, wn = w & 1;
  const int lin = blockIdx.x;                       // 1024 blocks
  const int wid = (lin & 7) * 128 + (lin >> 3);     // chunked XCD swizzle
  const int m0 = (wid >> 2) * 128;
  const int n0 = (wid & 3) * 128;
  const int lda = 256, ldb = 256;
  const bf16_t* Abase = A + (size_t)m0 * lda;
  const bf16_t* Bbase = Bt + (size_t)n0 * ldb;

  f32x4 acc[4][4] = {};

  auto stage = [&](int kt, int bufi) {
    const int k0 = kt * 64;
#pragma unroll
    for (int rnd = 0; rnd < 4; ++rnd) {
      int idx = rnd * 256 + tid;
      int row = idx >> 3, d = idx & 7;
      int sc = d ^ (row & 7);
      GLL16(Abase + row * lda + k0 + sc * 8, &Al[bufi][idx * 8]);
    }
#pragma unroll
    for (int rnd = 0; rnd < 4; ++rnd) {
      int idx = rnd * 256 + tid;
      int row = idx >> 3, d = idx & 7;
      int sc = d ^ (row & 7);
      GLL16(Bbase + row * ldb + k0 + sc * 8, &Bl[bufi][idx * 8]);
    }
  };

  stage(0, 0);
  __syncthreads();
  int buf = 0;
  const int NK = 256 / 64;
  for (int kt = 0; kt < NK; ++kt) {
    if (kt + 1 < NK) stage(kt + 1, buf ^ 1);
#pragma unroll
    for (int kk = 0; kk < 2; ++kk) {
      bf16x8 af[4], bfr[4];
#pragma unroll
      for (int mi = 0; mi < 4; ++mi) {
        int row = wm * 64 + mi * 16 + r;
        int cc = (kk * 4 + g) ^ (row & 7);
        af[mi] = *(const bf16x8*)&Al[buf][row * 64 + cc * 8];
      }
#pragma unroll
      for (int ni = 0; ni < 4; ++ni) {
        int row = wn * 64 + ni * 16 + r;
        int cc = (kk * 4 + g) ^ (row & 7);
        bfr[ni] = *(const bf16x8*)&Bl[buf][row * 64 + cc * 8];
      }
#pragma unroll
      for (int mi = 0; mi < 4; ++mi)
#pragma unroll
        for (int ni = 0; ni < 4; ++ni)
          acc[mi][ni] = __builtin_amdgcn_mfma_f32_16x16x32_bf16(af[mi], bfr[ni], acc[mi][ni], 0, 0, 0);
    }
    __syncthreads();
    buf ^= 1;
  }

#pragma unroll
  for (int mi = 0; mi < 4; ++mi) {
    int row0 = m0 + wm * 64 + mi * 16 + g * 4;
#pragma unroll
    for (int ni = 0; ni < 4; ++ni) {
      int col = n0 + wn * 64 + ni * 16 + r;
      float bv = bias[col];
#pragma unroll
      for (int i = 0; i < 4; ++i) {
        size_t off = (size_t)(row0 + i) * 512 + col;
        Out[off] = acc[mi][ni][i] + bv + X[off];
      }
    }
  }
}

// ---------------- launch ----------------
extern "C" void kernel_launch(void* const* d_in, const int* in_sizes, int n_in,
                              void* d_out, int out_size, void* d_ws, size_t ws_size,
                              hipStream_t stream) {
  const float* X    = (const float*)d_in[0];  // [16,2048,512]
  const float* Wqkv = (const float*)d_in[1];  // [1,512,768]
  const float* bqkv = (const float*)d_in[2];  // [768]
  const float* Wout = (const float*)d_in[3];  // [1,256,512]
  const float* bout = (const float*)d_in[4];  // [512]
  float* out = (float*)d_out;

  char* ws = (char*)d_ws;
  // layout (~85.5 MB): ctx0|ctx1 32M | WqkvT 768K | WoutT 256K | Q 16M | K 16M
  //                    | Vt/ctxF 16M | ml 512K
  bf16_t* Xbf   = (bf16_t*)ws;                     // 32MB; after gemm_qkv it holds ctx0|ctx1
  bf16_t* ctx0  = (bf16_t*)ws;                     // 16MB partial (split 0)
  bf16_t* ctx1  = (bf16_t*)(ws + 16777216);        // 16MB partial (split 1)
  bf16_t* WqkvT = (bf16_t*)(ws + 33554432);
  bf16_t* WoutT = (bf16_t*)(ws + 34340864);
  bf16_t* Qb    = (bf16_t*)(ws + 34603008);
  bf16_t* Kb    = (bf16_t*)(ws + 51380224);
  bf16_t* Vt    = (bf16_t*)(ws + 68157440);        // V^T; after attn reused for merged ctx
  float2* ml    = (float2*)(ws + 84934656);        // 2 x 32768 x float2

  bf16_t* ctxF  = Vt;                               // merged ctx written over dead V^T

  cast_all_kernel<<<2048, 256, 0, stream>>>(X, Xbf, Wqkv, Wout, WqkvT, WoutT);
  gemm_qkv_kernel<<<1536, 256, 0, stream>>>(Xbf, WqkvT, bqkv, Qb, Kb, Vt);
  attn_kernel<<<512, 256, 0, stream>>>(Qb, Kb, Vt, ctx0, ml);
  merge_kernel<<<8192, 256, 0, stream>>>(ctx0, ctx1, ml, ctxF);
  gemm_out_kernel<<<1024, 256, 0, stream>>>(ctxF, WoutT, bout, X, out);
}

// Round 12
// 295.765 us; speedup vs baseline: 1.1156x; 1.1156x over previous
//
#include <hip/hip_runtime.h>

typedef __bf16 bf16_t;
typedef __attribute__((ext_vector_type(8))) __bf16 bf16x8;
typedef __attribute__((ext_vector_type(4))) __bf16 bf16x4;
typedef __attribute__((ext_vector_type(4))) float f32x4;
typedef __attribute__((ext_vector_type(16))) float f32x16;
typedef __attribute__((ext_vector_type(4))) unsigned u32x4;

// async global->LDS, 16B per lane. LDS dest must be wave-uniform base + lane*16.
#define GLL16(gsrc, ldst)                                                                   \
  __builtin_amdgcn_global_load_lds(                                                         \
      (const __attribute__((address_space(1))) unsigned int*)(gsrc),                        \
      (__attribute__((address_space(3))) unsigned int*)(ldst), 16, 0, 0)

// v_permlane32_swap_b32: a'[0:31]=a[0:31], a'[32:63]=b[0:31]; b'[0:31]=a[32:63], b'[32:63]=b[32:63]
#define SWAP32(x, y) asm("v_permlane32_swap_b32 %0, %1" : "+v"(x), "+v"(y))

// ---------------- problem dims ----------------
#define BATCH 16
#define TT    2048
#define DD    512
#define FF    256
#define MTOT  (BATCH * TT)   // 32768

static __device__ __forceinline__ unsigned pk2(float a, float b) {
  unsigned short ua = __builtin_bit_cast(unsigned short, (bf16_t)a);
  unsigned short ub = __builtin_bit_cast(unsigned short, (bf16_t)b);
  return (unsigned)ua | ((unsigned)ub << 16);
}

// ---------------- merged cast kernel ----------------
__global__ __launch_bounds__(256) void cast_all_kernel(const float* __restrict__ x,
                                                       bf16_t* __restrict__ xb,
                                                       const float* __restrict__ Wqkv,
                                                       const float* __restrict__ Wout,
                                                       bf16_t* __restrict__ WqkvT,
                                                       bf16_t* __restrict__ WoutT) {
  const int t0 = blockIdx.x * blockDim.x + threadIdx.x;
  const int stride = gridDim.x * blockDim.x;
  const int n4 = (MTOT * DD) / 4;
  for (int i = t0; i < n4; i += stride) {
    float4 v = ((const float4*)x)[i];
    bf16x4 o;
    o[0] = (bf16_t)v.x; o[1] = (bf16_t)v.y; o[2] = (bf16_t)v.z; o[3] = (bf16_t)v.w;
    ((bf16x4*)xb)[i] = o;
  }
  for (int i = t0; i < 768 * 512 + 512 * 256; i += stride) {
    if (i < 768 * 512) {
      int n = i >> 9, k = i & 511;
      WqkvT[i] = (bf16_t)Wqkv[k * 768 + n];
    } else {
      int i2 = i - 768 * 512;
      int n = i2 >> 8, k = i2 & 255;
      WoutT[i2] = (bf16_t)Wout[k * 512 + n];
    }
  }
}

// ---------------- GEMM 1: X[32768,512] x WqkvT[768,512] -> Q,K row-major, V transposed ----
// 128x128 tile, BK=64 (8 K-steps), 64KB LDS -> 2 blocks/CU.  [round-11 WIN, kept]
__global__ __launch_bounds__(256) void gemm_qkv_kernel(const bf16_t* __restrict__ A,
                                                       const bf16_t* __restrict__ Bt,
                                                       const float* __restrict__ bias,
                                                       bf16_t* __restrict__ Qo,
                                                       bf16_t* __restrict__ Ko,
                                                       bf16_t* __restrict__ Vt) {
  __shared__ __align__(16) bf16_t Al[2][128 * 64];
  __shared__ __align__(16) bf16_t Bl[2][128 * 64];
  const int tid = threadIdx.x;
  const int l = tid & 63, w = tid >> 6;
  const int g = l >> 4, r = l & 15;
  const int wm = w >> 1, wn = w & 1;
  const int lin = blockIdx.x;                       // 1536 blocks
  const int wid = (lin & 7) * 192 + (lin >> 3);     // bijective chunked XCD swizzle
  const int m0 = (wid / 6) * 128;
  const int n0 = (wid % 6) * 128;
  const int lda = 512, ldb = 512;
  const bf16_t* Abase = A + (size_t)m0 * lda;
  const bf16_t* Bbase = Bt + (size_t)n0 * ldb;

  f32x4 acc[4][4] = {};

  auto stage = [&](int kt, int bufi) {
    const int k0 = kt * 64;
#pragma unroll
    for (int rnd = 0; rnd < 4; ++rnd) {             // 128 rows x 8 chunks of 16B
      int idx = rnd * 256 + tid;
      int row = idx >> 3, d = idx & 7;
      int sc = d ^ (row & 7);
      GLL16(Abase + row * lda + k0 + sc * 8, &Al[bufi][idx * 8]);
    }
#pragma unroll
    for (int rnd = 0; rnd < 4; ++rnd) {
      int idx = rnd * 256 + tid;
      int row = idx >> 3, d = idx & 7;
      int sc = d ^ (row & 7);
      GLL16(Bbase + row * ldb + k0 + sc * 8, &Bl[bufi][idx * 8]);
    }
  };

  stage(0, 0);
  __syncthreads();
  int buf = 0;
  const int NK = 512 / 64;
  for (int kt = 0; kt < NK; ++kt) {
    if (kt + 1 < NK) stage(kt + 1, buf ^ 1);
#pragma unroll
    for (int kk = 0; kk < 2; ++kk) {
      bf16x8 af[4], bfr[4];
#pragma unroll
      for (int mi = 0; mi < 4; ++mi) {
        int row = wm * 64 + mi * 16 + r;
        int cc = (kk * 4 + g) ^ (row & 7);
        af[mi] = *(const bf16x8*)&Al[buf][row * 64 + cc * 8];
      }
#pragma unroll
      for (int ni = 0; ni < 4; ++ni) {
        int row = wn * 64 + ni * 16 + r;
        int cc = (kk * 4 + g) ^ (row & 7);
        bfr[ni] = *(const bf16x8*)&Bl[buf][row * 64 + cc * 8];
      }
#pragma unroll
      for (int mi = 0; mi < 4; ++mi)
#pragma unroll
        for (int ni = 0; ni < 4; ++ni)
          acc[mi][ni] = __builtin_amdgcn_mfma_f32_16x16x32_bf16(af[mi], bfr[ni], acc[mi][ni], 0, 0, 0);
    }
    __syncthreads();
    buf ^= 1;
  }

  const int qsel = n0 >> 8;
#pragma unroll
  for (int mi = 0; mi < 4; ++mi) {
    int row0 = m0 + wm * 64 + mi * 16 + g * 4;
#pragma unroll
    for (int ni = 0; ni < 4; ++ni) {
      int col = n0 + wn * 64 + ni * 16 + r;
      float bv = bias[col];
      int cl = col & 255;
      if (qsel == 2) {
        bf16x4 pk;
#pragma unroll
        for (int i = 0; i < 4; ++i) pk[i] = (bf16_t)(acc[mi][ni][i] + bv);
        int b = row0 >> 11, t0 = row0 & 2047;
        *(bf16x4*)&Vt[((size_t)(b * 256 + cl)) * 2048 + t0] = pk;
      } else {
        bf16_t* dst = (qsel == 0) ? Qo : Ko;
#pragma unroll
        for (int i = 0; i < 4; ++i)
          dst[(size_t)(row0 + i) * 256 + cl] = (bf16_t)(acc[mi][ni][i] + bv);
      }
    }
  }
}

// ---------------- flash attention (kv-split x2, 32x32x16 MFMA, q_w=32) ----------------
// [exact round-10 version — measured 116.2 µs; round-11 st-split reverted]
// 512 blocks = 16 batches x 16 qblk(128) x 2 kv-splits, XCD-chunk-swizzled.
// 256 threads = 4 waves, each wave owns 32 q rows (q = lane&31, lane-local).
// KVBLK=32, LDS 64KB dbuf -> 2 blocks/CU, 2 waves/SIMD. P in-register via
// cvt-pack + permlane32_swap.
__global__ __launch_bounds__(256, 2) void attn_kernel(const bf16_t* __restrict__ Q,
                                                      const bf16_t* __restrict__ K,
                                                      const bf16_t* __restrict__ Vt,
                                                      bf16_t* __restrict__ ctxp,
                                                      float2* __restrict__ ml) {
  __shared__ __align__(16) bf16_t Kl[2][32 * 256];   // [kv][f], 512B rows, 16B-chunk ^= row&7
  __shared__ __align__(16) bf16_t Vl[2][256 * 32];   // [f][kv], 64B rows, 16B-chunk ^= row&3
  const int tid = threadIdx.x;
  const int l = tid & 63, w = tid >> 6;              // 4 waves
  const int hi = l >> 5, q31 = l & 31;
  const int lin = blockIdx.x;                        // 512 blocks
  const int wid = (lin & 7) * 64 + (lin >> 3);       // chunked XCD swizzle (2 batches/XCD)
  const int b = wid >> 5;
  const int qblk = wid & 15;
  const int s = (wid >> 4) & 1;                      // kv split
  const int q0 = qblk * 128 + w * 32;
  const int kvbase = s * 1024;
  const bf16_t* Kb = K + ((size_t)b * TT) * 256;
  const bf16_t* Vb = Vt + (size_t)b * 256 * TT;

  // Q B-fragments: B[k][q], k = kf*16 + hi*8 + j, q = q31
  bf16x8 qf[16];
  const bf16_t* Qrow = Q + ((size_t)(b * TT) + q0 + q31) * 256;
#pragma unroll
  for (int kf = 0; kf < 16; ++kf) qf[kf] = *(const bf16x8*)(Qrow + kf * 16 + hi * 8);

  f32x16 cacc[8] = {};
  float m_run = -3.0e38f, l_run = 0.0f;

  auto stage = [&](int kv0, int bi) {
#pragma unroll
    for (int rnd = 0; rnd < 4; ++rnd) {  // K tile: 32 rows x 32 chunks of 16B
      int idx = rnd * 256 + tid;
      int row = idx >> 5, d = idx & 31;
      int sc = d ^ (row & 7);
      GLL16(Kb + (size_t)(kv0 + row) * 256 + sc * 8, &Kl[bi][idx * 8]);
    }
#pragma unroll
    for (int rnd = 0; rnd < 4; ++rnd) {  // V tile: 256 rows x 4 chunks of 16B
      int idx = rnd * 256 + tid;
      int R = idx >> 2, d = idx & 3;
      int c = d ^ (R & 3);
      GLL16(Vb + (size_t)R * TT + kv0 + c * 8, &Vl[bi][idx * 8]);
    }
  };

  stage(kvbase, 0);
  __syncthreads();
  int buf = 0;

  for (int t = 0; t < 32; ++t) {
    const int kv0 = kvbase + t * 32;
    if (t + 1 < 32) stage(kv0 + 32, buf ^ 1);      // prefetch next tile under compute

    // S^T[kv32][q32] = K-tile x Q : A-frag row kv=q31, k = kf*16+hi*8+j
    f32x16 st = {};
    __builtin_amdgcn_s_setprio(1);
#pragma unroll
    for (int kf = 0; kf < 16; ++kf) {
      int chunk = (2 * kf + hi) ^ (q31 & 7);
      bf16x8 kfr = *(const bf16x8*)&Kl[buf][q31 * 256 + chunk * 8];
      st = __builtin_amdgcn_mfma_f32_32x32x16_bf16(kfr, qf[kf], st, 0, 0, 0);
    }
    __builtin_amdgcn_s_setprio(0);

    // online softmax; lane state for q=q31, 16 kv values/lane (partner lane+32 has other 16)
    float tmax = -3.0e38f;
#pragma unroll
    for (int i = 0; i < 16; ++i) tmax = fmaxf(tmax, st[i] * 0.0625f);
    tmax = fmaxf(tmax, __shfl_xor(tmax, 32));
    if (!__all(tmax - m_run <= 8.0f)) {            // defer-max
      float mnew = fmaxf(m_run, tmax);
      float alpha = __expf(m_run - mnew);
      l_run *= alpha;
#pragma unroll
      for (int fc = 0; fc < 8; ++fc)
#pragma unroll
        for (int i = 0; i < 16; ++i) cacc[fc][i] *= alpha;
      m_run = mnew;
    }
    float psum = 0.0f;
    float p[16];
#pragma unroll
    for (int i = 0; i < 16; ++i) {
      p[i] = __expf(st[i] * 0.0625f - m_run);      // bounded by e^8; kv=(i&3)+8*(i>>2)+4*hi
      psum += p[i];
    }
    psum += __shfl_xor(psum, 32);
    l_run += psum;

    // P -> bf16 B-frags in-register: pack kv-pairs, swap halves across lane32 boundary.
    unsigned u00 = pk2(p[0], p[1]),  u01 = pk2(p[2], p[3]);
    unsigned u10 = pk2(p[4], p[5]),  u11 = pk2(p[6], p[7]);
    unsigned u20 = pk2(p[8], p[9]),  u21 = pk2(p[10], p[11]);
    unsigned u30 = pk2(p[12], p[13]), u31 = pk2(p[14], p[15]);
    SWAP32(u00, u10);  // u00 -> elems(0,1), u10 -> elems(4,5)
    SWAP32(u01, u11);  // u01 -> elems(2,3), u11 -> elems(6,7)
    SWAP32(u20, u30);
    SWAP32(u21, u31);
    u32x4 w0 = {u00, u01, u10, u11};
    u32x4 w1 = {u20, u21, u30, u31};
    bf16x8 pf0 = __builtin_bit_cast(bf16x8, w0);   // P^T[kv 0..15][q], k=hi*8+j
    bf16x8 pf1 = __builtin_bit_cast(bf16x8, w1);   // P^T[kv 16..31][q]

    // PV: ctx^T[f][q] += V^T x P^T ; A-frag row f_loc=q31, k = kv_half local
    __builtin_amdgcn_s_setprio(1);
#pragma unroll
    for (int fc = 0; fc < 8; ++fc) {
      int R = fc * 32 + q31;
      bf16x8 vf0 = *(const bf16x8*)&Vl[buf][R * 32 + ((hi ^ (R & 3)) * 8)];
      bf16x8 vf1 = *(const bf16x8*)&Vl[buf][R * 32 + (((2 + hi) ^ (R & 3)) * 8)];
      cacc[fc] = __builtin_amdgcn_mfma_f32_32x32x16_bf16(vf0, pf0, cacc[fc], 0, 0, 0);
      cacc[fc] = __builtin_amdgcn_mfma_f32_32x32x16_bf16(vf1, pf1, cacc[fc], 0, 0, 0);
    }
    __builtin_amdgcn_s_setprio(0);

    __syncthreads();         // drains vmcnt(0): next tile staged; all waves done with buf
    buf ^= 1;
  }

  // epilogue: normalized partial ctx[q][f], f = fc*32 + 8*qd + 4*hi + i
  float inv = 1.0f / l_run;
  bf16_t* crow = ctxp + (size_t)s * (MTOT * 256) + ((size_t)(b * TT) + q0 + q31) * 256;
#pragma unroll
  for (int fc = 0; fc < 8; ++fc) {
#pragma unroll
    for (int qd = 0; qd < 4; ++qd) {
      bf16x4 o;
#pragma unroll
      for (int i = 0; i < 4; ++i) o[i] = (bf16_t)(cacc[fc][4 * qd + i] * inv);
      *(bf16x4*)(crow + fc * 32 + 8 * qd + 4 * hi) = o;
    }
  }
  if (l < 32) {
    float2 v; v.x = m_run; v.y = l_run;
    ml[s * MTOT + b * TT + q0 + l] = v;
  }
}

// ---------------- merge the two kv-split partials ----------------
__global__ __launch_bounds__(256) void merge_kernel(const bf16_t* __restrict__ c0,
                                                    const bf16_t* __restrict__ c1,
                                                    const float2* __restrict__ ml,
                                                    bf16_t* __restrict__ out) {
  int t = blockIdx.x * 256 + threadIdx.x;          // 32768*64 threads
  int row = t >> 6;
  int fo = (t & 63) * 4;
  float2 a = ml[row];
  float2 bm = ml[MTOT + row];
  float M = fmaxf(a.x, bm.x);
  float w0 = a.y * __expf(a.x - M);
  float w1 = bm.y * __expf(bm.x - M);
  float inv = 1.0f / (w0 + w1);
  w0 *= inv; w1 *= inv;
  size_t off = (size_t)row * 256 + fo;
  bf16x4 v0 = *(const bf16x4*)(c0 + off);
  bf16x4 v1 = *(const bf16x4*)(c1 + off);
  bf16x4 o;
#pragma unroll
  for (int i = 0; i < 4; ++i) o[i] = (bf16_t)((float)v0[i] * w0 + (float)v1[i] * w1);
  *(bf16x4*)(out + off) = o;
}

// ---------------- GEMM 2: ctx[32768,256] x WoutT[512,256] + bias + X -> out fp32 --------
// BK=64 (4 K-steps), 64KB LDS.  [round-11 WIN, kept]
__global__ __launch_bounds__(256) void gemm_out_kernel(const bf16_t* __restrict__ A,
                                                       const bf16_t* __restrict__ Bt,
                                                       const float* __restrict__ bias,
                                                       const float* __restrict__ X,
                                                       float* __restrict__ Out) {
  __shared__ __align__(16) bf16_t Al[2][128 * 64];
  __shared__ __align__(16) bf16_t Bl[2][128 * 64];
  const int tid = threadIdx.x;
  const int l = tid & 63, w = tid >> 6;
  const int g = l >> 4, r = l & 15;
  const int wm = w >> 1, wn = w & 1;
  const int lin = blockIdx.x;                       // 1024 blocks
  const int wid = (lin & 7) * 128 + (lin >> 3);     // chunked XCD swizzle
  const int m0 = (wid >> 2) * 128;
  const int n0 = (wid & 3) * 128;
  const int lda = 256, ldb = 256;
  const bf16_t* Abase = A + (size_t)m0 * lda;
  const bf16_t* Bbase = Bt + (size_t)n0 * ldb;

  f32x4 acc[4][4] = {};

  auto stage = [&](int kt, int bufi) {
    const int k0 = kt * 64;
#pragma unroll
    for (int rnd = 0; rnd < 4; ++rnd) {
      int idx = rnd * 256 + tid;
      int row = idx >> 3, d = idx & 7;
      int sc = d ^ (row & 7);
      GLL16(Abase + row * lda + k0 + sc * 8, &Al[bufi][idx * 8]);
    }
#pragma unroll
    for (int rnd = 0; rnd < 4; ++rnd) {
      int idx = rnd * 256 + tid;
      int row = idx >> 3, d = idx & 7;
      int sc = d ^ (row & 7);
      GLL16(Bbase + row * ldb + k0 + sc * 8, &Bl[bufi][idx * 8]);
    }
  };

  stage(0, 0);
  __syncthreads();
  int buf = 0;
  const int NK = 256 / 64;
  for (int kt = 0; kt < NK; ++kt) {
    if (kt + 1 < NK) stage(kt + 1, buf ^ 1);
#pragma unroll
    for (int kk = 0; kk < 2; ++kk) {
      bf16x8 af[4], bfr[4];
#pragma unroll
      for (int mi = 0; mi < 4; ++mi) {
        int row = wm * 64 + mi * 16 + r;
        int cc = (kk * 4 + g) ^ (row & 7);
        af[mi] = *(const bf16x8*)&Al[buf][row * 64 + cc * 8];
      }
#pragma unroll
      for (int ni = 0; ni < 4; ++ni) {
        int row = wn * 64 + ni * 16 + r;
        int cc = (kk * 4 + g) ^ (row & 7);
        bfr[ni] = *(const bf16x8*)&Bl[buf][row * 64 + cc * 8];
      }
#pragma unroll
      for (int mi = 0; mi < 4; ++mi)
#pragma unroll
        for (int ni = 0; ni < 4; ++ni)
          acc[mi][ni] = __builtin_amdgcn_mfma_f32_16x16x32_bf16(af[mi], bfr[ni], acc[mi][ni], 0, 0, 0);
    }
    __syncthreads();
    buf ^= 1;
  }

#pragma unroll
  for (int mi = 0; mi < 4; ++mi) {
    int row0 = m0 + wm * 64 + mi * 16 + g * 4;
#pragma unroll
    for (int ni = 0; ni < 4; ++ni) {
      int col = n0 + wn * 64 + ni * 16 + r;
      float bv = bias[col];
#pragma unroll
      for (int i = 0; i < 4; ++i) {
        size_t off = (size_t)(row0 + i) * 512 + col;
        Out[off] = acc[mi][ni][i] + bv + X[off];
      }
    }
  }
}

// ---------------- launch ----------------
extern "C" void kernel_launch(void* const* d_in, const int* in_sizes, int n_in,
                              void* d_out, int out_size, void* d_ws, size_t ws_size,
                              hipStream_t stream) {
  const float* X    = (const float*)d_in[0];  // [16,2048,512]
  const float* Wqkv = (const float*)d_in[1];  // [1,512,768]
  const float* bqkv = (const float*)d_in[2];  // [768]
  const float* Wout = (const float*)d_in[3];  // [1,256,512]
  const float* bout = (const float*)d_in[4];  // [512]
  float* out = (float*)d_out;

  char* ws = (char*)d_ws;
  // layout (~85.5 MB): ctx0|ctx1 32M | WqkvT 768K | WoutT 256K | Q 16M | K 16M
  //                    | Vt/ctxF 16M | ml 512K
  bf16_t* Xbf   = (bf16_t*)ws;                     // 32MB; after gemm_qkv it holds ctx0|ctx1
  bf16_t* ctx0  = (bf16_t*)ws;                     // 16MB partial (split 0)
  bf16_t* ctx1  = (bf16_t*)(ws + 16777216);        // 16MB partial (split 1)
  bf16_t* WqkvT = (bf16_t*)(ws + 33554432);
  bf16_t* WoutT = (bf16_t*)(ws + 34340864);
  bf16_t* Qb    = (bf16_t*)(ws + 34603008);
  bf16_t* Kb    = (bf16_t*)(ws + 51380224);
  bf16_t* Vt    = (bf16_t*)(ws + 68157440);        // V^T; after attn reused for merged ctx
  float2* ml    = (float2*)(ws + 84934656);        // 2 x 32768 x float2

  bf16_t* ctxF  = Vt;                               // merged ctx written over dead V^T

  cast_all_kernel<<<2048, 256, 0, stream>>>(X, Xbf, Wqkv, Wout, WqkvT, WoutT);
  gemm_qkv_kernel<<<1536, 256, 0, stream>>>(Xbf, WqkvT, bqkv, Qb, Kb, Vt);
  attn_kernel<<<512, 256, 0, stream>>>(Qb, Kb, Vt, ctx0, ml);
  merge_kernel<<<8192, 256, 0, stream>>>(ctx0, ctx1, ml, ctxF);
  gemm_out_kernel<<<1024, 256, 0, stream>>>(ctxF, WoutT, bout, X, out);
}